// Round 12
// baseline (206.000 us; speedup 1.0000x reference)
//
#include <hip/hip_runtime.h>
#include <hip/hip_bf16.h>

// Problem constants
#define B_   4
#define S_   2048
#define H_   1024
#define NH_  16
#define HD_  64
#define M_   8192   // B_*S_
#define K_   1024

using bf16x8 = __bf16 __attribute__((ext_vector_type(8)));
using f32x4  = float __attribute__((ext_vector_type(4)));
using f32x16 = float __attribute__((ext_vector_type(16)));

__device__ inline f32x4 mfma16(bf16x8 a, bf16x8 b, f32x4 c) {
    return __builtin_amdgcn_mfma_f32_16x16x32_bf16(a, b, c, 0, 0, 0);
}
__device__ inline f32x16 mfma32(bf16x8 a, bf16x8 b, f32x16 c) {
    return __builtin_amdgcn_mfma_f32_32x32x16_bf16(a, b, c, 0, 0, 0);
}

__device__ inline unsigned short f2bf(float f) {
    __hip_bfloat16 h = __float2bfloat16(f);
    return *reinterpret_cast<unsigned short*>(&h);
}

// pack 2 f32 -> 2 bf16 in one u32 (lo = first arg)
__device__ inline unsigned cvt_pk_bf16(float lo, float hi) {
    unsigned r;
    asm("v_cvt_pk_bf16_f32 %0, %1, %2" : "=v"(r) : "v"(lo), "v"(hi));
    return r;
}

// swap lanes 32-63 of a with lanes 0-31 of b (both registers updated)
__device__ inline void perm32swap(unsigned &a, unsigned &b) {
    asm("v_permlane32_swap_b32 %0, %1" : "+v"(a), "+v"(b));
}

// async global->LDS, 16B per lane; LDS dest = wave-uniform base + lane*16
__device__ inline void gload_lds16(const unsigned short* g, unsigned short* l) {
    __builtin_amdgcn_global_load_lds(
        (const __attribute__((address_space(1))) void*)g,
        (__attribute__((address_space(3))) void*)l, 16, 0, 0);
}

#define EXP2F(x) __builtin_amdgcn_exp2f(x)

// ---------------------------------------------------------------------------
// Workspace layout (ushort elements unless noted):
//   xb   @ 0          (M*K)  bf16 x   [reused as attn-out]
//   wqkv @ 8388608    [3072 x 1024] stacked Q,K,V weights; wob @ 11534336
//   qbuf @ 12582912   (B,NH,S,HD) bf16, RoPE'd, pre-scaled by 0.125*log2(e)
//   kbuf @ 20971520   (B,NH,S,HD) bf16, RoPE'd
//   vtb  @ 29360128   (B,NH,HD,S) bf16 (transposed V)
//   ropeb @ 37748736  f32 [S][32][2] interleaved {cos,sin}
//   biasb @ 38010880  f32 [B*S] additive softmax bias (0 / -inf)
//   kflagb@ biasb+8192  int [B][32]  1 = 64-key tile fully unmasked
// ---------------------------------------------------------------------------

// fp32->bf16 conversion for x + weights, PLUS (last 256 blocks) the rope
// {cos,sin} table, additive mask bias, and per-64-key-tile unmasked flags.
__global__ __launch_bounds__(256) void prep_convert(
    const float* __restrict__ x,  const float* __restrict__ wq,
    const float* __restrict__ wk, const float* __restrict__ wv,
    const float* __restrict__ wo, unsigned short* __restrict__ ws,
    const int* __restrict__ mask, float2* __restrict__ ropeb,
    float* __restrict__ biasb, int* __restrict__ kflagb)
{
    size_t u = (size_t)blockIdx.x * 256 + threadIdx.x;
    if (u < 3145728) {                          // conversion region
        const float* src; unsigned short* dst; size_t off;
        if (u < 2097152)      { src = x;  dst = ws;            off = u * 4; }
        else if (u < 2359296) { src = wq; dst = ws + 8388608;  off = (u - 2097152) * 4; }
        else if (u < 2621440) { src = wk; dst = ws + 9437184;  off = (u - 2359296) * 4; }
        else if (u < 2883584) { src = wv; dst = ws + 10485760; off = (u - 2621440) * 4; }
        else                  { src = wo; dst = ws + 11534336; off = (u - 2883584) * 4; }
        float4 v = *reinterpret_cast<const float4*>(src + off);
        ushort4 o;
        o.x = f2bf(v.x); o.y = f2bf(v.y); o.z = f2bf(v.z); o.w = f2bf(v.w);
        *reinterpret_cast<ushort4*>(dst + off) = o;
    } else {                                    // table region (65536 threads)
        int idx = (int)(u - 3145728);
        int pos = idx >> 5, i = idx & 31;
        float inv = expf(-(float)(2 * i) * (9.210340371976184f / 64.0f));
        float ang = (float)pos * inv;
        float2 cs; cs.x = cosf(ang); cs.y = sinf(ang);
        ropeb[idx] = cs;                        // layout [pos][i] = {c,s}
        if (idx < B_ * S_)
            biasb[idx] = mask[idx] ? 0.0f : -__builtin_inff();
        if (idx < B_ * 32) {                    // 4 batches x 32 key-tiles
            int b = idx >> 5, kt = idx & 31;
            int all = 1;
            for (int j = 0; j < 64; j++)
                all &= (mask[b * S_ + kt * 64 + j] != 0) ? 1 : 0;
            kflagb[idx] = all;
        }
    }
}

// ---------------------------------------------------------------------------
// GEMM, 128x128 tile, 4-phase double-buffered pipeline (round-8 proven form).
// MODE 0: fused QKV (cols 0-1023 Q RoPE+scale, 1024-2047 K RoPE, 2048+ V^T);
//         Q/K use swapped-operand MFMA (acc = D^T) for in-thread RoPE pairs.
// MODE 1: output projection, fp32 out.
// ---------------------------------------------------------------------------
template<int MODE>
__global__ __launch_bounds__(256, 2) void gemm_main(
    const unsigned short* __restrict__ A,
    const unsigned short* __restrict__ W,
    unsigned short* __restrict__ qbuf, unsigned short* __restrict__ kbuf,
    unsigned short* __restrict__ vtb, float* __restrict__ fout,
    const float* __restrict__ ropeb)
{
    __shared__ alignas(16) unsigned short Al[2][128 * 64];
    __shared__ alignas(16) unsigned short Bl[2][128 * 64];

    const int t = threadIdx.x;
    const int l = t & 63;
    const int w = t >> 6;
    const int lane_r = l & 15, lane_g = l >> 4;
    const int bn = blockIdx.x, bm = blockIdx.y;
    const size_t rowbase = (size_t)bm * 128;
    const int colbase = bn * 128;
    const int wm = (w >> 1) * 64, wn = (w & 1) * 64;
    const int which = (MODE == 0) ? (colbase >> 10) : 3;   // 0 Q, 1 K, 2 V, 3 WO
    const float scale = (which == 0) ? 0.18033688089184827f : 1.0f;

    const int glrow  = l >> 3;
    const int glslot = (l & 7) ^ glrow;
    const unsigned short* ga = A + (rowbase + w * 8 + glrow) * K_ + glslot * 8;
    const unsigned short* gb = W + (size_t)(colbase + w * 8 + glrow) * K_ + glslot * 8;

#define GLA(bi, kt, i) gload_lds16(ga + (size_t)(i) * 32 * K_ + (kt) * 64, \
                                   &Al[bi][((i) * 32 + w * 8) * 64]);
#define GLB(bi, kt, i) gload_lds16(gb + (size_t)(i) * 32 * K_ + (kt) * 64, \
                                   &Bl[bi][((i) * 32 + w * 8) * 64]);
#define RDA(mt, kk) { int rowa = wm + (mt) * 16 + lane_r;                      \
    af[mt][kk] = *reinterpret_cast<const bf16x8*>((const char*)Al[cur] +       \
        ((rowa * 128 + (kk) * 64 + lane_g * 16) ^ ((rowa & 7) << 4))); }
#define RDB(nt, kk) { int rowb = wn + (nt) * 16 + lane_r;                      \
    bfr[nt][kk] = *reinterpret_cast<const bf16x8*>((const char*)Bl[cur] +      \
        ((rowb * 128 + (kk) * 64 + lane_g * 16) ^ ((rowb & 7) << 4))); }
#define MM(mb, nb)                                                             \
    if (MODE == 0 && which <= 1) {                                             \
        _Pragma("unroll")                                                      \
        for (int a = (nb); a < (nb) + 2; a++)                                  \
            _Pragma("unroll")                                                  \
            for (int b2 = (mb); b2 < (mb) + 2; b2++) {                         \
                acc[a][b2] = mfma16(bfr[a][0], af[b2][0], acc[a][b2]);         \
                acc[a][b2] = mfma16(bfr[a][1], af[b2][1], acc[a][b2]);         \
            }                                                                  \
    } else {                                                                   \
        _Pragma("unroll")                                                      \
        for (int mt = (mb); mt < (mb) + 2; mt++)                               \
            _Pragma("unroll")                                                  \
            for (int nt = (nb); nt < (nb) + 2; nt++) {                         \
                acc[mt][nt] = mfma16(af[mt][0], bfr[nt][0], acc[mt][nt]);      \
                acc[mt][nt] = mfma16(af[mt][1], bfr[nt][1], acc[mt][nt]);      \
            }                                                                  \
    }
#define BARS __builtin_amdgcn_s_barrier();                                     \
             asm volatile("s_waitcnt lgkmcnt(0)" ::: "memory");                \
             __builtin_amdgcn_s_setprio(1);
#define BARE __builtin_amdgcn_s_setprio(0); __builtin_amdgcn_s_barrier();

    f32x4 zero4 = {0.f, 0.f, 0.f, 0.f};
    f32x4 acc[4][4];
#pragma unroll
    for (int a = 0; a < 4; a++)
#pragma unroll
        for (int b2 = 0; b2 < 4; b2++) acc[a][b2] = zero4;

    GLA(0, 0, 0) GLA(0, 0, 1) GLA(0, 0, 2) GLA(0, 0, 3)
    GLB(0, 0, 0) GLB(0, 0, 1) GLB(0, 0, 2) GLB(0, 0, 3)
    __syncthreads();

    for (int kt = 0; kt < 16; kt++) {
        const int cur = kt & 1, nxt = cur ^ 1;
        const bool pf = (kt < 15);
        bf16x8 af[4][2], bfr[4][2];
        RDA(0, 0) RDA(0, 1) RDA(1, 0) RDA(1, 1)
        RDB(0, 0) RDB(0, 1) RDB(1, 0) RDB(1, 1)
        if (pf) { GLA(nxt, kt + 1, 0) GLA(nxt, kt + 1, 1) GLA(nxt, kt + 1, 2) }
        BARS MM(0, 0) BARE
        RDB(2, 0) RDB(2, 1) RDB(3, 0) RDB(3, 1)
        if (pf) { GLA(nxt, kt + 1, 3) GLB(nxt, kt + 1, 0) GLB(nxt, kt + 1, 1) }
        BARS MM(0, 2) BARE
        RDA(2, 0) RDA(2, 1) RDA(3, 0) RDA(3, 1)
        if (pf) { GLB(nxt, kt + 1, 2) GLB(nxt, kt + 1, 3) }
        BARS MM(2, 2) BARE
        __builtin_amdgcn_s_setprio(1);
        MM(2, 0)
        __builtin_amdgcn_s_setprio(0);
        asm volatile("s_waitcnt vmcnt(0)" ::: "memory");
        __builtin_amdgcn_s_barrier();
    }
#undef GLA
#undef GLB
#undef RDA
#undef RDB
#undef MM
#undef BARS
#undef BARE

    // ---- epilogues ----
    if (MODE == 1) {
        float* out = fout;
#pragma unroll
        for (int mt = 0; mt < 4; mt++)
#pragma unroll
            for (int nt = 0; nt < 4; nt++)
#pragma unroll
                for (int i = 0; i < 4; i++) {
                    size_t r = rowbase + wm + mt * 16 + lane_g * 4 + i;
                    int n = colbase + wn + nt * 16 + lane_r;
                    out[r * 1024 + n] = acc[mt][nt][i];
                }
    } else if (which <= 1) {
        unsigned short* out = which ? kbuf : qbuf;
#pragma unroll
        for (int a = 0; a < 4; a++) {
            int nbase = (colbase & 1023) + wn + a * 16 + 4 * lane_g;
            int h = nbase >> 6, d0 = nbase & 63;
#pragma unroll
            for (int b2 = 0; b2 < 4; b2++) {
                size_t r = rowbase + wm + b2 * 16 + lane_r;
                int bb  = (int)(r >> 11);
                int pos = (int)(r & 2047);
                float4 cs = *reinterpret_cast<const float4*>(
                    ropeb + pos * 64 + d0);          // {c0,s0,c1,s1}
                float a0 = acc[a][b2][0], a1 = acc[a][b2][1];
                float a2 = acc[a][b2][2], a3 = acc[a][b2][3];
                float o0 = (a0 * cs.x - a1 * cs.y) * scale;
                float o1 = (a0 * cs.y + a1 * cs.x) * scale;
                float o2 = (a2 * cs.z - a3 * cs.w) * scale;
                float o3 = (a2 * cs.w + a3 * cs.z) * scale;
                uint2 o;
                o.x = cvt_pk_bf16(o0, o1);
                o.y = cvt_pk_bf16(o2, o3);
                *reinterpret_cast<uint2*>(
                    out + (((size_t)(bb * NH_ + h)) * S_ + pos) * 64 + d0) = o;
            }
        }
    } else {
#pragma unroll
        for (int a = 0; a < 4; a++)
#pragma unroll
            for (int b2 = 0; b2 < 4; b2++) {
                size_t rr = rowbase + wm + a * 16 + lane_g * 4;
                int n = (colbase & 1023) + wn + b2 * 16 + lane_r;
                int bb  = (int)(rr >> 11);
                int pos = (int)(rr & 2047);
                int h = n >> 6, d = n & 63;
                ushort4 o;
                o.x = f2bf(acc[a][b2][0]); o.y = f2bf(acc[a][b2][1]);
                o.z = f2bf(acc[a][b2][2]); o.w = f2bf(acc[a][b2][3]);
                *reinterpret_cast<ushort4*>(
                    vtb + (((size_t)(bb * NH_ + h)) * 64 + d) * S_ + pos) = o;
            }
    }
}

// ---------------------------------------------------------------------------
// Flash attention: 32x32 swapped-operand, P in-register, 2 q-blocks/wave.
// ROUND-12: 128-key MACRO-TILES -- one barrier pair serves TWO 64-key
// sub-tiles (compute body per sub identical to round 11). Barriers 32 -> 16;
// drain/skew amortizes 2x. LDS 64KB/block (2 blocks/CU = 128KB <= 160KB).
// Fast path per 64-key sub-tile: zero16 C-init; masked path: bias C-init.
// ---------------------------------------------------------------------------
__global__ __launch_bounds__(256, 2) void attn_fwd(
    const unsigned short* __restrict__ qb, const unsigned short* __restrict__ kb,
    const unsigned short* __restrict__ vt, const float* __restrict__ biasb,
    const int* __restrict__ kflagb, unsigned short* __restrict__ ao)
{
    __shared__ alignas(16) unsigned short Kl[2][2][64 * 64];  // [dbuf][sub]
    __shared__ alignas(16) unsigned short Vl[2][2][64 * 64];

    // XCD-clustering swizzle (bijective: 512 % 8 == 0): 8 bh per XCD.
    const int bid = blockIdx.x;
    const int xcd = bid & 7, idx = bid >> 3;
    const int bh = xcd * 8 + (idx >> 3);
    const int qt = idx & 7;                   // 8 q-tiles of 256 rows
    const int b = bh >> 4, h = bh & 15;

    const int t = threadIdx.x, l = t & 63, w = t >> 6;
    const int lr = l & 31;       // q column / frag row
    const int hi = l >> 5;
    const int row8 = lr & 7;     // read-swizzle key

    const unsigned short* qp = qb + (size_t)bh * S_ * 64;
    const unsigned short* kp = kb + (size_t)bh * S_ * 64;
    const unsigned short* vp = vt + (size_t)bh * 64 * S_;
    const float* bp = biasb + (size_t)b * S_;
    const int* kfl = kflagb + b * 32;

    // Q B-frags: qf[qbk][ks] = Q[qrow][d=16ks+8hi+j], qrow = base + 32qbk + lr
    bf16x8 qf[2][4];
#pragma unroll
    for (int qbk = 0; qbk < 2; qbk++) {
        int qrow = qt * 256 + w * 64 + qbk * 32 + lr;
#pragma unroll
        for (int ks = 0; ks < 4; ks++)
            qf[qbk][ks] = *reinterpret_cast<const bf16x8*>(
                qp + (size_t)qrow * 64 + ks * 16 + hi * 8);
    }

    f32x16 zero16;
#pragma unroll
    for (int r = 0; r < 16; r++) zero16[r] = 0.f;

    f32x16 oacc[2][2];
#pragma unroll
    for (int qbk = 0; qbk < 2; qbk++)
#pragma unroll
        for (int r = 0; r < 16; r++) { oacc[qbk][0][r] = 0.f; oacc[qbk][1][r] = 0.f; }
    float lsum[2] = {0.f, 0.f};

    // staging: wave w covers rows [16w,16w+16) of each sub-tile, 2 chunks of 8
    const int grr = l >> 3;
    const int gss = ((l & 7) ^ grr) * 8;      // source-swizzled 16B slot

    // stage one 128-key macro-tile (2 x 64-key subs) into buffer bi
#define STAGE(bi, mt)                                                          \
    {                                                                          \
        _Pragma("unroll")                                                      \
        for (int sub = 0; sub < 2; sub++) {                                    \
            _Pragma("unroll")                                                  \
            for (int c = 0; c < 2; c++) {                                      \
                int rbase = w * 16 + c * 8;                                    \
                gload_lds16(kp + (size_t)((mt) * 128 + sub * 64 + rbase + grr) * 64 + gss, \
                            &Kl[bi][sub][rbase * 64]);                         \
                gload_lds16(vp + (size_t)(rbase + grr) * S_ + (mt) * 128 + sub * 64 + gss, \
                            &Vl[bi][sub][rbase * 64]);                         \
            }                                                                  \
        }                                                                      \
    }

    // QK^T with C-init C0/C1 per key-half (shared by both q-blocks)
#define QKBLOCK(KLP, C0, C1)                                                   \
    {                                                                          \
        __builtin_amdgcn_s_setprio(1);                                         \
        _Pragma("unroll")                                                      \
        for (int T = 0; T < 2; T++) {                                          \
            int rowb = (32 * T + lr) * 128;                                    \
            bf16x8 kf0 = *reinterpret_cast<const bf16x8*>(                     \
                (const char*)(KLP) + rowb + ((hi ^ row8) << 4));               \
            sacc[0][T] = mfma32(kf0, qf[0][0], T ? (C1) : (C0));               \
            sacc[1][T] = mfma32(kf0, qf[1][0], T ? (C1) : (C0));               \
            _Pragma("unroll")                                                  \
            for (int ks = 1; ks < 4; ks++) {                                   \
                bf16x8 kfk = *reinterpret_cast<const bf16x8*>(                 \
                    (const char*)(KLP) + rowb + (((2 * ks + hi) ^ row8) << 4)); \
                sacc[0][T] = mfma32(kfk, qf[0][ks], sacc[0][T]);               \
                sacc[1][T] = mfma32(kfk, qf[1][ks], sacc[1][T]);               \
            }                                                                  \
        }                                                                      \
        __builtin_amdgcn_s_setprio(0);                                         \
    }

    STAGE(0, 0)

    for (int mt = 0; mt < 16; mt++) {
        const int cur = mt & 1;
        __syncthreads();               // drains vmcnt: buf[cur] ready; prev reads done
        if (mt < 15) STAGE(cur ^ 1, mt + 1)

#pragma unroll
        for (int sub = 0; sub < 2; sub++) {
            const int kt64 = mt * 2 + sub;     // 64-key tile index
            f32x16 sacc[2][2];
            if (kfl[kt64]) {
                QKBLOCK(Kl[cur][sub], zero16, zero16)
            } else {
                f32x16 binit[2];
#pragma unroll
                for (int T = 0; T < 2; T++)
#pragma unroll
                    for (int g = 0; g < 4; g++) {
                        float4 bv = *reinterpret_cast<const float4*>(
                            bp + kt64 * 64 + T * 32 + g * 8 + hi * 4);
                        binit[T][g * 4 + 0] = bv.x; binit[T][g * 4 + 1] = bv.y;
                        binit[T][g * 4 + 2] = bv.z; binit[T][g * 4 + 3] = bv.w;
                    }
                QKBLOCK(Kl[cur][sub], binit[0], binit[1])
            }

            // p = exp2(s), sum, pack, permlane-redistribute (per q-block)
            bf16x8 pa[2][4];
#pragma unroll
            for (int qbk = 0; qbk < 2; qbk++) {
                unsigned u[2][8];
                float r0 = 0.f, r1 = 0.f, r2 = 0.f, r3 = 0.f;
#pragma unroll
                for (int T = 0; T < 2; T++) {
                    float p[16];
#pragma unroll
                    for (int r = 0; r < 16; r++) p[r] = EXP2F(sacc[qbk][T][r]);
#pragma unroll
                    for (int r = 0; r < 16; r += 4) {
                        r0 += p[r]; r1 += p[r + 1]; r2 += p[r + 2]; r3 += p[r + 3];
                    }
#pragma unroll
                    for (int bq = 0; bq < 4; bq++) {
                        u[T][bq * 2 + 0] = cvt_pk_bf16(p[bq * 4 + 0], p[bq * 4 + 1]);
                        u[T][bq * 2 + 1] = cvt_pk_bf16(p[bq * 4 + 2], p[bq * 4 + 3]);
                    }
                }
                lsum[qbk] += (r0 + r1) + (r2 + r3);
#pragma unroll
                for (int ks = 0; ks < 4; ks++) {
                    int T = ks >> 1, e = ks & 1;
                    unsigned a0 = u[T][4 * e + 0], b0 = u[T][4 * e + 2];
                    unsigned a1 = u[T][4 * e + 1], b1 = u[T][4 * e + 3];
                    perm32swap(a0, b0);
                    perm32swap(a1, b1);
                    unsigned q4[4] = {a0, a1, b0, b1};
                    pa[qbk][ks] = *reinterpret_cast<const bf16x8*>(q4);
                }
            }

            // O^T += V^T x P^T : each vf feeds both q-blocks
            __builtin_amdgcn_s_setprio(1);
#pragma unroll
            for (int dt = 0; dt < 2; dt++) {
                int rowb = (32 * dt + lr) * 128;
#pragma unroll
                for (int ks = 0; ks < 4; ks++) {
                    bf16x8 vf = *reinterpret_cast<const bf16x8*>(
                        (const char*)Vl[cur][sub] + rowb + (((2 * ks + hi) ^ row8) << 4));
                    oacc[0][dt] = mfma32(vf, pa[0][ks], oacc[0][dt]);
                    oacc[1][dt] = mfma32(vf, pa[1][ks], oacc[1][dt]);
                }
            }
            __builtin_amdgcn_s_setprio(0);
        }
    }
#undef STAGE
#undef QKBLOCK

    // epilogue: O row d = 32dt+8g+4hi+m, col q = lr (per q-block)
#pragma unroll
    for (int qbk = 0; qbk < 2; qbk++) {
        float ls = lsum[qbk];
        ls += __shfl_xor(ls, 32);
        float rl = 1.0f / ls;
        size_t obase = ((size_t)(b * S_) + qt * 256 + w * 64 + qbk * 32 + lr) * 1024 + h * 64;
#pragma unroll
        for (int dt = 0; dt < 2; dt++)
#pragma unroll
            for (int g = 0; g < 4; g++) {
                uint2 o;
                o.x = cvt_pk_bf16(oacc[qbk][dt][g * 4 + 0] * rl, oacc[qbk][dt][g * 4 + 1] * rl);
                o.y = cvt_pk_bf16(oacc[qbk][dt][g * 4 + 2] * rl, oacc[qbk][dt][g * 4 + 3] * rl);
                *reinterpret_cast<uint2*>(ao + obase + 32 * dt + 8 * g + 4 * hi) = o;
            }
    }
}

// ---------------------------------------------------------------------------
extern "C" void kernel_launch(void* const* d_in, const int* in_sizes, int n_in,
                              void* d_out, int out_size, void* d_ws, size_t ws_size,
                              hipStream_t stream)
{
    const float* x  = (const float*)d_in[0];
    const float* wq = (const float*)d_in[1];
    const float* wk = (const float*)d_in[2];
    const float* wv = (const float*)d_in[3];
    const float* wo = (const float*)d_in[4];
    const int* mask = (const int*)d_in[5];

    unsigned short* ws   = (unsigned short*)d_ws;
    unsigned short* xb   = ws;                 // M*K bf16; reused as attn-out
    unsigned short* wqkv = ws + 8388608;       // [3072 x 1024] stacked Q,K,V
    unsigned short* wob  = ws + 11534336;
    unsigned short* qbuf = ws + 12582912;
    unsigned short* kbuf = ws + 20971520;
    unsigned short* vtb  = ws + 29360128;
    float* ropeb = (float*)(ws + 37748736);    // [S][32][2] {cos,sin}
    float* biasb = (float*)(ws + 38010880);
    int* kflagb  = (int*)(biasb + 8192);
    unsigned short* aob = xb;                  // alias: xb dead after QKV GEMM

    // conversion + rope/bias/flag tables in one launch
    prep_convert<<<12544, 256, 0, stream>>>(
        x, wq, wk, wv, wo, ws, mask, (float2*)ropeb, biasb, kflagb);

    // Fused QKV projection, 128^2 4-phase (Q scale = 0.125*log2e in epilogue)
    gemm_main<0><<<dim3(24, 64), 256, 0, stream>>>(
        xb, wqkv, qbuf, kbuf, vtb, nullptr, ropeb);

    attn_fwd<<<512, 256, 0, stream>>>(qbuf, kbuf, vtb, biasb, kflagb, aob);

    gemm_main<1><<<dim3(8, 64), 256, 0, stream>>>(
        aob, wob, nullptr, nullptr, nullptr, (float*)d_out, nullptr);
}

// Round 13
// 198.164 us; speedup vs baseline: 1.0395x; 1.0395x over previous
//
#include <hip/hip_runtime.h>
#include <hip/hip_bf16.h>

// Problem constants
#define B_   4
#define S_   2048
#define H_   1024
#define NH_  16
#define HD_  64
#define M_   8192   // B_*S_
#define K_   1024

using bf16x8 = __bf16 __attribute__((ext_vector_type(8)));
using f32x4  = float __attribute__((ext_vector_type(4)));
using f32x16 = float __attribute__((ext_vector_type(16)));

__device__ inline f32x4 mfma16(bf16x8 a, bf16x8 b, f32x4 c) {
    return __builtin_amdgcn_mfma_f32_16x16x32_bf16(a, b, c, 0, 0, 0);
}
__device__ inline f32x16 mfma32(bf16x8 a, bf16x8 b, f32x16 c) {
    return __builtin_amdgcn_mfma_f32_32x32x16_bf16(a, b, c, 0, 0, 0);
}

__device__ inline unsigned short f2bf(float f) {
    __hip_bfloat16 h = __float2bfloat16(f);
    return *reinterpret_cast<unsigned short*>(&h);
}

// pack 2 f32 -> 2 bf16 in one u32 (lo = first arg)
__device__ inline unsigned cvt_pk_bf16(float lo, float hi) {
    unsigned r;
    asm("v_cvt_pk_bf16_f32 %0, %1, %2" : "=v"(r) : "v"(lo), "v"(hi));
    return r;
}

// swap lanes 32-63 of a with lanes 0-31 of b (both registers updated)
__device__ inline void perm32swap(unsigned &a, unsigned &b) {
    asm("v_permlane32_swap_b32 %0, %1" : "+v"(a), "+v"(b));
}

// async global->LDS, 16B per lane; LDS dest = wave-uniform base + lane*16
__device__ inline void gload_lds16(const unsigned short* g, unsigned short* l) {
    __builtin_amdgcn_global_load_lds(
        (const __attribute__((address_space(1))) void*)g,
        (__attribute__((address_space(3))) void*)l, 16, 0, 0);
}

#define EXP2F(x) __builtin_amdgcn_exp2f(x)

// ---------------------------------------------------------------------------
// Workspace layout (ushort elements unless noted):
//   xb   @ 0          (M*K)  bf16 x   [reused as attn-out]
//   wqkv @ 8388608    [3072 x 1024] stacked Q,K,V weights; wob @ 11534336
//   qbuf @ 12582912   (B,NH,S,HD) bf16, RoPE'd, pre-scaled by 0.125*log2(e)
//   kbuf @ 20971520   (B,NH,S,HD) bf16, RoPE'd
//   vtb  @ 29360128   (B,NH,HD,S) bf16 (transposed V)
//   ropeb @ 37748736  f32 [S][32][2] interleaved {cos,sin}
//   biasb @ 38010880  f32 [B*S] additive softmax bias (0 / -inf)
//   kflagb@ biasb+8192  int [B][32]  1 = 64-key tile fully unmasked
// ---------------------------------------------------------------------------

// fp32->bf16 conversion for x + weights, PLUS (last 256 blocks) the rope
// {cos,sin} table, additive mask bias, and per-64-key-tile unmasked flags.
__global__ __launch_bounds__(256) void prep_convert(
    const float* __restrict__ x,  const float* __restrict__ wq,
    const float* __restrict__ wk, const float* __restrict__ wv,
    const float* __restrict__ wo, unsigned short* __restrict__ ws,
    const int* __restrict__ mask, float2* __restrict__ ropeb,
    float* __restrict__ biasb, int* __restrict__ kflagb)
{
    size_t u = (size_t)blockIdx.x * 256 + threadIdx.x;
    if (u < 3145728) {                          // conversion region
        const float* src; unsigned short* dst; size_t off;
        if (u < 2097152)      { src = x;  dst = ws;            off = u * 4; }
        else if (u < 2359296) { src = wq; dst = ws + 8388608;  off = (u - 2097152) * 4; }
        else if (u < 2621440) { src = wk; dst = ws + 9437184;  off = (u - 2359296) * 4; }
        else if (u < 2883584) { src = wv; dst = ws + 10485760; off = (u - 2621440) * 4; }
        else                  { src = wo; dst = ws + 11534336; off = (u - 2883584) * 4; }
        float4 v = *reinterpret_cast<const float4*>(src + off);
        ushort4 o;
        o.x = f2bf(v.x); o.y = f2bf(v.y); o.z = f2bf(v.z); o.w = f2bf(v.w);
        *reinterpret_cast<ushort4*>(dst + off) = o;
    } else {                                    // table region (65536 threads)
        int idx = (int)(u - 3145728);
        int pos = idx >> 5, i = idx & 31;
        float inv = expf(-(float)(2 * i) * (9.210340371976184f / 64.0f));
        float ang = (float)pos * inv;
        float2 cs; cs.x = cosf(ang); cs.y = sinf(ang);
        ropeb[idx] = cs;                        // layout [pos][i] = {c,s}
        if (idx < B_ * S_)
            biasb[idx] = mask[idx] ? 0.0f : -__builtin_inff();
        if (idx < B_ * 32) {                    // 4 batches x 32 key-tiles
            int b = idx >> 5, kt = idx & 31;
            int all = 1;
            for (int j = 0; j < 64; j++)
                all &= (mask[b * S_ + kt * 64 + j] != 0) ? 1 : 0;
            kflagb[idx] = all;
        }
    }
}

// ---------------------------------------------------------------------------
// GEMM, 128x128 tile, 4-phase double-buffered pipeline (round-8 proven form).
// MODE 0: fused QKV (cols 0-1023 Q RoPE+scale, 1024-2047 K RoPE, 2048+ V^T);
//         Q/K use swapped-operand MFMA (acc = D^T) for in-thread RoPE pairs.
// MODE 1: output projection, fp32 out.
// ---------------------------------------------------------------------------
template<int MODE>
__global__ __launch_bounds__(256, 2) void gemm_main(
    const unsigned short* __restrict__ A,
    const unsigned short* __restrict__ W,
    unsigned short* __restrict__ qbuf, unsigned short* __restrict__ kbuf,
    unsigned short* __restrict__ vtb, float* __restrict__ fout,
    const float* __restrict__ ropeb)
{
    __shared__ alignas(16) unsigned short Al[2][128 * 64];
    __shared__ alignas(16) unsigned short Bl[2][128 * 64];

    const int t = threadIdx.x;
    const int l = t & 63;
    const int w = t >> 6;
    const int lane_r = l & 15, lane_g = l >> 4;
    const int bn = blockIdx.x, bm = blockIdx.y;
    const size_t rowbase = (size_t)bm * 128;
    const int colbase = bn * 128;
    const int wm = (w >> 1) * 64, wn = (w & 1) * 64;
    const int which = (MODE == 0) ? (colbase >> 10) : 3;   // 0 Q, 1 K, 2 V, 3 WO
    const float scale = (which == 0) ? 0.18033688089184827f : 1.0f;

    const int glrow  = l >> 3;
    const int glslot = (l & 7) ^ glrow;
    const unsigned short* ga = A + (rowbase + w * 8 + glrow) * K_ + glslot * 8;
    const unsigned short* gb = W + (size_t)(colbase + w * 8 + glrow) * K_ + glslot * 8;

#define GLA(bi, kt, i) gload_lds16(ga + (size_t)(i) * 32 * K_ + (kt) * 64, \
                                   &Al[bi][((i) * 32 + w * 8) * 64]);
#define GLB(bi, kt, i) gload_lds16(gb + (size_t)(i) * 32 * K_ + (kt) * 64, \
                                   &Bl[bi][((i) * 32 + w * 8) * 64]);
#define RDA(mt, kk) { int rowa = wm + (mt) * 16 + lane_r;                      \
    af[mt][kk] = *reinterpret_cast<const bf16x8*>((const char*)Al[cur] +       \
        ((rowa * 128 + (kk) * 64 + lane_g * 16) ^ ((rowa & 7) << 4))); }
#define RDB(nt, kk) { int rowb = wn + (nt) * 16 + lane_r;                      \
    bfr[nt][kk] = *reinterpret_cast<const bf16x8*>((const char*)Bl[cur] +      \
        ((rowb * 128 + (kk) * 64 + lane_g * 16) ^ ((rowb & 7) << 4))); }
#define MM(mb, nb)                                                             \
    if (MODE == 0 && which <= 1) {                                             \
        _Pragma("unroll")                                                      \
        for (int a = (nb); a < (nb) + 2; a++)                                  \
            _Pragma("unroll")                                                  \
            for (int b2 = (mb); b2 < (mb) + 2; b2++) {                         \
                acc[a][b2] = mfma16(bfr[a][0], af[b2][0], acc[a][b2]);         \
                acc[a][b2] = mfma16(bfr[a][1], af[b2][1], acc[a][b2]);         \
            }                                                                  \
    } else {                                                                   \
        _Pragma("unroll")                                                      \
        for (int mt = (mb); mt < (mb) + 2; mt++)                               \
            _Pragma("unroll")                                                  \
            for (int nt = (nb); nt < (nb) + 2; nt++) {                         \
                acc[mt][nt] = mfma16(af[mt][0], bfr[nt][0], acc[mt][nt]);      \
                acc[mt][nt] = mfma16(af[mt][1], bfr[nt][1], acc[mt][nt]);      \
            }                                                                  \
    }
#define BARS __builtin_amdgcn_s_barrier();                                     \
             asm volatile("s_waitcnt lgkmcnt(0)" ::: "memory");                \
             __builtin_amdgcn_s_setprio(1);
#define BARE __builtin_amdgcn_s_setprio(0); __builtin_amdgcn_s_barrier();

    f32x4 zero4 = {0.f, 0.f, 0.f, 0.f};
    f32x4 acc[4][4];
#pragma unroll
    for (int a = 0; a < 4; a++)
#pragma unroll
        for (int b2 = 0; b2 < 4; b2++) acc[a][b2] = zero4;

    GLA(0, 0, 0) GLA(0, 0, 1) GLA(0, 0, 2) GLA(0, 0, 3)
    GLB(0, 0, 0) GLB(0, 0, 1) GLB(0, 0, 2) GLB(0, 0, 3)
    __syncthreads();

    for (int kt = 0; kt < 16; kt++) {
        const int cur = kt & 1, nxt = cur ^ 1;
        const bool pf = (kt < 15);
        bf16x8 af[4][2], bfr[4][2];
        RDA(0, 0) RDA(0, 1) RDA(1, 0) RDA(1, 1)
        RDB(0, 0) RDB(0, 1) RDB(1, 0) RDB(1, 1)
        if (pf) { GLA(nxt, kt + 1, 0) GLA(nxt, kt + 1, 1) GLA(nxt, kt + 1, 2) }
        BARS MM(0, 0) BARE
        RDB(2, 0) RDB(2, 1) RDB(3, 0) RDB(3, 1)
        if (pf) { GLA(nxt, kt + 1, 3) GLB(nxt, kt + 1, 0) GLB(nxt, kt + 1, 1) }
        BARS MM(0, 2) BARE
        RDA(2, 0) RDA(2, 1) RDA(3, 0) RDA(3, 1)
        if (pf) { GLB(nxt, kt + 1, 2) GLB(nxt, kt + 1, 3) }
        BARS MM(2, 2) BARE
        __builtin_amdgcn_s_setprio(1);
        MM(2, 0)
        __builtin_amdgcn_s_setprio(0);
        asm volatile("s_waitcnt vmcnt(0)" ::: "memory");
        __builtin_amdgcn_s_barrier();
    }
#undef GLA
#undef GLB
#undef RDA
#undef RDB
#undef MM
#undef BARS
#undef BARE

    // ---- epilogues ----
    if (MODE == 1) {
        float* out = fout;
#pragma unroll
        for (int mt = 0; mt < 4; mt++)
#pragma unroll
            for (int nt = 0; nt < 4; nt++)
#pragma unroll
                for (int i = 0; i < 4; i++) {
                    size_t r = rowbase + wm + mt * 16 + lane_g * 4 + i;
                    int n = colbase + wn + nt * 16 + lane_r;
                    out[r * 1024 + n] = acc[mt][nt][i];
                }
    } else if (which <= 1) {
        unsigned short* out = which ? kbuf : qbuf;
#pragma unroll
        for (int a = 0; a < 4; a++) {
            int nbase = (colbase & 1023) + wn + a * 16 + 4 * lane_g;
            int h = nbase >> 6, d0 = nbase & 63;
#pragma unroll
            for (int b2 = 0; b2 < 4; b2++) {
                size_t r = rowbase + wm + b2 * 16 + lane_r;
                int bb  = (int)(r >> 11);
                int pos = (int)(r & 2047);
                float4 cs = *reinterpret_cast<const float4*>(
                    ropeb + pos * 64 + d0);          // {c0,s0,c1,s1}
                float a0 = acc[a][b2][0], a1 = acc[a][b2][1];
                float a2 = acc[a][b2][2], a3 = acc[a][b2][3];
                float o0 = (a0 * cs.x - a1 * cs.y) * scale;
                float o1 = (a0 * cs.y + a1 * cs.x) * scale;
                float o2 = (a2 * cs.z - a3 * cs.w) * scale;
                float o3 = (a2 * cs.w + a3 * cs.z) * scale;
                uint2 o;
                o.x = cvt_pk_bf16(o0, o1);
                o.y = cvt_pk_bf16(o2, o3);
                *reinterpret_cast<uint2*>(
                    out + (((size_t)(bb * NH_ + h)) * S_ + pos) * 64 + d0) = o;
            }
        }
    } else {
#pragma unroll
        for (int a = 0; a < 4; a++)
#pragma unroll
            for (int b2 = 0; b2 < 4; b2++) {
                size_t rr = rowbase + wm + a * 16 + lane_g * 4;
                int n = (colbase & 1023) + wn + b2 * 16 + lane_r;
                int bb  = (int)(rr >> 11);
                int pos = (int)(rr & 2047);
                int h = n >> 6, d = n & 63;
                ushort4 o;
                o.x = f2bf(acc[a][b2][0]); o.y = f2bf(acc[a][b2][1]);
                o.z = f2bf(acc[a][b2][2]); o.w = f2bf(acc[a][b2][3]);
                *reinterpret_cast<ushort4*>(
                    vtb + (((size_t)(bb * NH_ + h)) * 64 + d) * S_ + pos) = o;
            }
    }
}

// ---------------------------------------------------------------------------
// Flash attention (round-11 proven form, exact): 32x32 swapped-operand, P
// in-register, 2 q-blocks/wave, no fixed shift, per-64-key-tile fast path.
// Block = 4 waves x 64 q = 256 q; KVBLK = 64, double-buffered gload_lds.
// ---------------------------------------------------------------------------
__global__ __launch_bounds__(256, 2) void attn_fwd(
    const unsigned short* __restrict__ qb, const unsigned short* __restrict__ kb,
    const unsigned short* __restrict__ vt, const float* __restrict__ biasb,
    const int* __restrict__ kflagb, unsigned short* __restrict__ ao)
{
    __shared__ alignas(16) unsigned short Kl[2][64 * 64];
    __shared__ alignas(16) unsigned short Vl[2][64 * 64];

    // XCD-clustering swizzle (bijective: 512 % 8 == 0): 8 bh per XCD.
    const int bid = blockIdx.x;
    const int xcd = bid & 7, idx = bid >> 3;
    const int bh = xcd * 8 + (idx >> 3);
    const int qt = idx & 7;                   // 8 q-tiles of 256 rows
    const int b = bh >> 4, h = bh & 15;

    const int t = threadIdx.x, l = t & 63, w = t >> 6;
    const int lr = l & 31;       // q column / frag row
    const int hi = l >> 5;
    const int row8 = lr & 7;     // read-swizzle key

    const unsigned short* qp = qb + (size_t)bh * S_ * 64;
    const unsigned short* kp = kb + (size_t)bh * S_ * 64;
    const unsigned short* vp = vt + (size_t)bh * 64 * S_;
    const float* bp = biasb + (size_t)b * S_;
    const int* kfl = kflagb + b * 32;

    // Q B-frags: qf[qbk][ks] = Q[qrow][d=16ks+8hi+j], qrow = base + 32qbk + lr
    bf16x8 qf[2][4];
#pragma unroll
    for (int qbk = 0; qbk < 2; qbk++) {
        int qrow = qt * 256 + w * 64 + qbk * 32 + lr;
#pragma unroll
        for (int ks = 0; ks < 4; ks++)
            qf[qbk][ks] = *reinterpret_cast<const bf16x8*>(
                qp + (size_t)qrow * 64 + ks * 16 + hi * 8);
    }

    f32x16 zero16;
#pragma unroll
    for (int r = 0; r < 16; r++) zero16[r] = 0.f;

    f32x16 oacc[2][2];
#pragma unroll
    for (int qbk = 0; qbk < 2; qbk++)
#pragma unroll
        for (int r = 0; r < 16; r++) { oacc[qbk][0][r] = 0.f; oacc[qbk][1][r] = 0.f; }
    float lsum[2] = {0.f, 0.f};

    // staging: wave w covers rows [16w,16w+16) of both tiles, 2 chunks of 8
    const int grr = l >> 3;
    const int gss = ((l & 7) ^ grr) * 8;      // source-swizzled 16B slot

#define STAGE(bi, kt)                                                          \
    {                                                                          \
        _Pragma("unroll")                                                      \
        for (int c = 0; c < 2; c++) {                                          \
            int rbase = w * 16 + c * 8;                                        \
            gload_lds16(kp + (size_t)((kt) * 64 + rbase + grr) * 64 + gss,     \
                        &Kl[bi][rbase * 64]);                                  \
            gload_lds16(vp + (size_t)(rbase + grr) * S_ + (kt) * 64 + gss,     \
                        &Vl[bi][rbase * 64]);                                  \
        }                                                                      \
    }

    // QK^T with C-init C0/C1 per key-half (shared by both q-blocks)
#define QKBLOCK(C0, C1)                                                        \
    {                                                                          \
        __builtin_amdgcn_s_setprio(1);                                         \
        _Pragma("unroll")                                                      \
        for (int T = 0; T < 2; T++) {                                          \
            int rowb = (32 * T + lr) * 128;                                    \
            bf16x8 kf0 = *reinterpret_cast<const bf16x8*>(                     \
                (const char*)Kl[cur] + rowb + ((hi ^ row8) << 4));             \
            sacc[0][T] = mfma32(kf0, qf[0][0], T ? (C1) : (C0));               \
            sacc[1][T] = mfma32(kf0, qf[1][0], T ? (C1) : (C0));               \
            _Pragma("unroll")                                                  \
            for (int ks = 1; ks < 4; ks++) {                                   \
                bf16x8 kfk = *reinterpret_cast<const bf16x8*>(                 \
                    (const char*)Kl[cur] + rowb + (((2 * ks + hi) ^ row8) << 4)); \
                sacc[0][T] = mfma32(kfk, qf[0][ks], sacc[0][T]);               \
                sacc[1][T] = mfma32(kfk, qf[1][ks], sacc[1][T]);               \
            }                                                                  \
        }                                                                      \
        __builtin_amdgcn_s_setprio(0);                                         \
    }

    STAGE(0, 0)

    for (int kt = 0; kt < 32; kt++) {
        const int cur = kt & 1;
        __syncthreads();               // drains vmcnt: buf[cur] ready; prev reads done
        if (kt < 31) STAGE(cur ^ 1, kt + 1)

        f32x16 sacc[2][2];
        if (kfl[kt]) {
            // fast path: zero C-init straight from the persistent register
            QKBLOCK(zero16, zero16)
        } else {
            // masked path: C-init from bias table (0 / -inf)
            f32x16 binit[2];
#pragma unroll
            for (int T = 0; T < 2; T++)
#pragma unroll
                for (int g = 0; g < 4; g++) {
                    float4 bv = *reinterpret_cast<const float4*>(
                        bp + kt * 64 + T * 32 + g * 8 + hi * 4);
                    binit[T][g * 4 + 0] = bv.x; binit[T][g * 4 + 1] = bv.y;
                    binit[T][g * 4 + 2] = bv.z; binit[T][g * 4 + 3] = bv.w;
                }
            QKBLOCK(binit[0], binit[1])
        }

        // p = exp2(s), sum, pack, permlane-redistribute (per q-block)
        bf16x8 pa[2][4];
#pragma unroll
        for (int qbk = 0; qbk < 2; qbk++) {
            unsigned u[2][8];
            float r0 = 0.f, r1 = 0.f, r2 = 0.f, r3 = 0.f;
#pragma unroll
            for (int T = 0; T < 2; T++) {
                float p[16];
#pragma unroll
                for (int r = 0; r < 16; r++) p[r] = EXP2F(sacc[qbk][T][r]);
#pragma unroll
                for (int r = 0; r < 16; r += 4) {
                    r0 += p[r]; r1 += p[r + 1]; r2 += p[r + 2]; r3 += p[r + 3];
                }
#pragma unroll
                for (int bq = 0; bq < 4; bq++) {
                    u[T][bq * 2 + 0] = cvt_pk_bf16(p[bq * 4 + 0], p[bq * 4 + 1]);
                    u[T][bq * 2 + 1] = cvt_pk_bf16(p[bq * 4 + 2], p[bq * 4 + 3]);
                }
            }
            lsum[qbk] += (r0 + r1) + (r2 + r3);
#pragma unroll
            for (int ks = 0; ks < 4; ks++) {
                int T = ks >> 1, e = ks & 1;
                unsigned a0 = u[T][4 * e + 0], b0 = u[T][4 * e + 2];
                unsigned a1 = u[T][4 * e + 1], b1 = u[T][4 * e + 3];
                perm32swap(a0, b0);
                perm32swap(a1, b1);
                unsigned q4[4] = {a0, a1, b0, b1};
                pa[qbk][ks] = *reinterpret_cast<const bf16x8*>(q4);
            }
        }

        // O^T += V^T x P^T : each vf feeds both q-blocks
        __builtin_amdgcn_s_setprio(1);
#pragma unroll
        for (int dt = 0; dt < 2; dt++) {
            int rowb = (32 * dt + lr) * 128;
#pragma unroll
            for (int ks = 0; ks < 4; ks++) {
                bf16x8 vf = *reinterpret_cast<const bf16x8*>(
                    (const char*)Vl[cur] + rowb + (((2 * ks + hi) ^ row8) << 4));
                oacc[0][dt] = mfma32(vf, pa[0][ks], oacc[0][dt]);
                oacc[1][dt] = mfma32(vf, pa[1][ks], oacc[1][dt]);
            }
        }
        __builtin_amdgcn_s_setprio(0);
    }
#undef STAGE
#undef QKBLOCK

    // epilogue: O row d = 32dt+8g+4hi+m, col q = lr (per q-block)
#pragma unroll
    for (int qbk = 0; qbk < 2; qbk++) {
        float ls = lsum[qbk];
        ls += __shfl_xor(ls, 32);
        float rl = 1.0f / ls;
        size_t obase = ((size_t)(b * S_) + qt * 256 + w * 64 + qbk * 32 + lr) * 1024 + h * 64;
#pragma unroll
        for (int dt = 0; dt < 2; dt++)
#pragma unroll
            for (int g = 0; g < 4; g++) {
                uint2 o;
                o.x = cvt_pk_bf16(oacc[qbk][dt][g * 4 + 0] * rl, oacc[qbk][dt][g * 4 + 1] * rl);
                o.y = cvt_pk_bf16(oacc[qbk][dt][g * 4 + 2] * rl, oacc[qbk][dt][g * 4 + 3] * rl);
                *reinterpret_cast<uint2*>(ao + obase + 32 * dt + 8 * g + 4 * hi) = o;
            }
    }
}

// ---------------------------------------------------------------------------
extern "C" void kernel_launch(void* const* d_in, const int* in_sizes, int n_in,
                              void* d_out, int out_size, void* d_ws, size_t ws_size,
                              hipStream_t stream)
{
    const float* x  = (const float*)d_in[0];
    const float* wq = (const float*)d_in[1];
    const float* wk = (const float*)d_in[2];
    const float* wv = (const float*)d_in[3];
    const float* wo = (const float*)d_in[4];
    const int* mask = (const int*)d_in[5];

    unsigned short* ws   = (unsigned short*)d_ws;
    unsigned short* xb   = ws;                 // M*K bf16; reused as attn-out
    unsigned short* wqkv = ws + 8388608;       // [3072 x 1024] stacked Q,K,V
    unsigned short* wob  = ws + 11534336;
    unsigned short* qbuf = ws + 12582912;
    unsigned short* kbuf = ws + 20971520;
    unsigned short* vtb  = ws + 29360128;
    float* ropeb = (float*)(ws + 37748736);    // [S][32][2] {cos,sin}
    float* biasb = (float*)(ws + 38010880);
    int* kflagb  = (int*)(biasb + 8192);
    unsigned short* aob = xb;                  // alias: xb dead after QKV GEMM

    // conversion + rope/bias/flag tables in one launch
    prep_convert<<<12544, 256, 0, stream>>>(
        x, wq, wk, wv, wo, ws, mask, (float2*)ropeb, biasb, kflagb);

    // Fused QKV projection, 128^2 4-phase (Q scale = 0.125*log2e in epilogue)
    gemm_main<0><<<dim3(24, 64), 256, 0, stream>>>(
        xb, wqkv, qbuf, kbuf, vtb, nullptr, ropeb);

    attn_fwd<<<512, 256, 0, stream>>>(qbuf, kbuf, vtb, biasb, kflagb, aob);

    gemm_main<1><<<dim3(8, 64), 256, 0, stream>>>(
        aob, wob, nullptr, nullptr, nullptr, (float*)d_out, nullptr);
}

// Round 14
// 194.801 us; speedup vs baseline: 1.0575x; 1.0173x over previous
//
#include <hip/hip_runtime.h>
#include <hip/hip_bf16.h>

// Problem constants
#define B_   4
#define S_   2048
#define H_   1024
#define NH_  16
#define HD_  64
#define M_   8192   // B_*S_
#define K_   1024

using bf16x8 = __bf16 __attribute__((ext_vector_type(8)));
using f32x4  = float __attribute__((ext_vector_type(4)));
using f32x16 = float __attribute__((ext_vector_type(16)));

__device__ inline f32x4 mfma16(bf16x8 a, bf16x8 b, f32x4 c) {
    return __builtin_amdgcn_mfma_f32_16x16x32_bf16(a, b, c, 0, 0, 0);
}
__device__ inline f32x16 mfma32(bf16x8 a, bf16x8 b, f32x16 c) {
    return __builtin_amdgcn_mfma_f32_32x32x16_bf16(a, b, c, 0, 0, 0);
}

__device__ inline unsigned short f2bf(float f) {
    __hip_bfloat16 h = __float2bfloat16(f);
    return *reinterpret_cast<unsigned short*>(&h);
}

// pack 2 f32 -> 2 bf16 in one u32 (lo = first arg)
__device__ inline unsigned cvt_pk_bf16(float lo, float hi) {
    unsigned r;
    asm("v_cvt_pk_bf16_f32 %0, %1, %2" : "=v"(r) : "v"(lo), "v"(hi));
    return r;
}

// swap lanes 32-63 of a with lanes 0-31 of b (both registers updated)
__device__ inline void perm32swap(unsigned &a, unsigned &b) {
    asm("v_permlane32_swap_b32 %0, %1" : "+v"(a), "+v"(b));
}

// async global->LDS, 16B per lane; LDS dest = wave-uniform base + lane*16
__device__ inline void gload_lds16(const unsigned short* g, unsigned short* l) {
    __builtin_amdgcn_global_load_lds(
        (const __attribute__((address_space(1))) void*)g,
        (__attribute__((address_space(3))) void*)l, 16, 0, 0);
}

#define EXP2F(x) __builtin_amdgcn_exp2f(x)

// ---------------------------------------------------------------------------
// Workspace layout (ushort elements unless noted):
//   xb   @ 0          (M*K)  bf16 x   [reused as attn-out]
//   wqkv @ 8388608    [3072 x 1024] stacked Q,K,V weights; wob @ 11534336
//   qbuf @ 12582912   (B,NH,S,HD) bf16, RoPE'd, pre-scaled by 0.125*log2(e)
//   kbuf @ 20971520   (B,NH,S,HD) bf16, RoPE'd
//   vtb  @ 29360128   (B,NH,HD,S) bf16 (transposed V)
//   ropeb @ 37748736  f32 [S][32][2] interleaved {cos,sin}
//   biasb @ 38010880  f32 [B*S] additive softmax bias (0 / -inf)
//   kflagb@ biasb+8192  int [B][32]  1 = 64-key tile fully unmasked
// ---------------------------------------------------------------------------

// fp32->bf16 conversion for x + weights, PLUS (last 256 blocks) the rope
// {cos,sin} table, additive mask bias, and per-64-key-tile unmasked flags.
__global__ __launch_bounds__(256) void prep_convert(
    const float* __restrict__ x,  const float* __restrict__ wq,
    const float* __restrict__ wk, const float* __restrict__ wv,
    const float* __restrict__ wo, unsigned short* __restrict__ ws,
    const int* __restrict__ mask, float2* __restrict__ ropeb,
    float* __restrict__ biasb, int* __restrict__ kflagb)
{
    size_t u = (size_t)blockIdx.x * 256 + threadIdx.x;
    if (u < 3145728) {                          // conversion region
        const float* src; unsigned short* dst; size_t off;
        if (u < 2097152)      { src = x;  dst = ws;            off = u * 4; }
        else if (u < 2359296) { src = wq; dst = ws + 8388608;  off = (u - 2097152) * 4; }
        else if (u < 2621440) { src = wk; dst = ws + 9437184;  off = (u - 2359296) * 4; }
        else if (u < 2883584) { src = wv; dst = ws + 10485760; off = (u - 2621440) * 4; }
        else                  { src = wo; dst = ws + 11534336; off = (u - 2883584) * 4; }
        float4 v = *reinterpret_cast<const float4*>(src + off);
        ushort4 o;
        o.x = f2bf(v.x); o.y = f2bf(v.y); o.z = f2bf(v.z); o.w = f2bf(v.w);
        *reinterpret_cast<ushort4*>(dst + off) = o;
    } else {                                    // table region (65536 threads)
        int idx = (int)(u - 3145728);
        int pos = idx >> 5, i = idx & 31;
        float inv = expf(-(float)(2 * i) * (9.210340371976184f / 64.0f));
        float ang = (float)pos * inv;
        float2 cs; cs.x = cosf(ang); cs.y = sinf(ang);
        ropeb[idx] = cs;                        // layout [pos][i] = {c,s}
        if (idx < B_ * S_)
            biasb[idx] = mask[idx] ? 0.0f : -__builtin_inff();
        if (idx < B_ * 32) {                    // 4 batches x 32 key-tiles
            int b = idx >> 5, kt = idx & 31;
            int all = 1;
            for (int j = 0; j < 64; j++)
                all &= (mask[b * S_ + kt * 64 + j] != 0) ? 1 : 0;
            kflagb[idx] = all;
        }
    }
}

// ---------------------------------------------------------------------------
// GEMM, 128x128 tile, 4-phase double-buffered pipeline (round-8 proven form).
// MODE 0: fused QKV (cols 0-1023 Q RoPE+scale, 1024-2047 K RoPE, 2048+ V^T);
//         Q/K use swapped-operand MFMA (acc = D^T) for in-thread RoPE pairs.
// MODE 1: output projection, fp32 out.
// ---------------------------------------------------------------------------
template<int MODE>
__global__ __launch_bounds__(256, 2) void gemm_main(
    const unsigned short* __restrict__ A,
    const unsigned short* __restrict__ W,
    unsigned short* __restrict__ qbuf, unsigned short* __restrict__ kbuf,
    unsigned short* __restrict__ vtb, float* __restrict__ fout,
    const float* __restrict__ ropeb)
{
    __shared__ alignas(16) unsigned short Al[2][128 * 64];
    __shared__ alignas(16) unsigned short Bl[2][128 * 64];

    const int t = threadIdx.x;
    const int l = t & 63;
    const int w = t >> 6;
    const int lane_r = l & 15, lane_g = l >> 4;
    const int bn = blockIdx.x, bm = blockIdx.y;
    const size_t rowbase = (size_t)bm * 128;
    const int colbase = bn * 128;
    const int wm = (w >> 1) * 64, wn = (w & 1) * 64;
    const int which = (MODE == 0) ? (colbase >> 10) : 3;   // 0 Q, 1 K, 2 V, 3 WO
    const float scale = (which == 0) ? 0.18033688089184827f : 1.0f;

    const int glrow  = l >> 3;
    const int glslot = (l & 7) ^ glrow;
    const unsigned short* ga = A + (rowbase + w * 8 + glrow) * K_ + glslot * 8;
    const unsigned short* gb = W + (size_t)(colbase + w * 8 + glrow) * K_ + glslot * 8;

#define GLA(bi, kt, i) gload_lds16(ga + (size_t)(i) * 32 * K_ + (kt) * 64, \
                                   &Al[bi][((i) * 32 + w * 8) * 64]);
#define GLB(bi, kt, i) gload_lds16(gb + (size_t)(i) * 32 * K_ + (kt) * 64, \
                                   &Bl[bi][((i) * 32 + w * 8) * 64]);
#define RDA(mt, kk) { int rowa = wm + (mt) * 16 + lane_r;                      \
    af[mt][kk] = *reinterpret_cast<const bf16x8*>((const char*)Al[cur] +       \
        ((rowa * 128 + (kk) * 64 + lane_g * 16) ^ ((rowa & 7) << 4))); }
#define RDB(nt, kk) { int rowb = wn + (nt) * 16 + lane_r;                      \
    bfr[nt][kk] = *reinterpret_cast<const bf16x8*>((const char*)Bl[cur] +      \
        ((rowb * 128 + (kk) * 64 + lane_g * 16) ^ ((rowb & 7) << 4))); }
#define MM(mb, nb)                                                             \
    if (MODE == 0 && which <= 1) {                                             \
        _Pragma("unroll")                                                      \
        for (int a = (nb); a < (nb) + 2; a++)                                  \
            _Pragma("unroll")                                                  \
            for (int b2 = (mb); b2 < (mb) + 2; b2++) {                         \
                acc[a][b2] = mfma16(bfr[a][0], af[b2][0], acc[a][b2]);         \
                acc[a][b2] = mfma16(bfr[a][1], af[b2][1], acc[a][b2]);         \
            }                                                                  \
    } else {                                                                   \
        _Pragma("unroll")                                                      \
        for (int mt = (mb); mt < (mb) + 2; mt++)                               \
            _Pragma("unroll")                                                  \
            for (int nt = (nb); nt < (nb) + 2; nt++) {                         \
                acc[mt][nt] = mfma16(af[mt][0], bfr[nt][0], acc[mt][nt]);      \
                acc[mt][nt] = mfma16(af[mt][1], bfr[nt][1], acc[mt][nt]);      \
            }                                                                  \
    }
#define BARS __builtin_amdgcn_s_barrier();                                     \
             asm volatile("s_waitcnt lgkmcnt(0)" ::: "memory");                \
             __builtin_amdgcn_s_setprio(1);
#define BARE __builtin_amdgcn_s_setprio(0); __builtin_amdgcn_s_barrier();

    f32x4 zero4 = {0.f, 0.f, 0.f, 0.f};
    f32x4 acc[4][4];
#pragma unroll
    for (int a = 0; a < 4; a++)
#pragma unroll
        for (int b2 = 0; b2 < 4; b2++) acc[a][b2] = zero4;

    GLA(0, 0, 0) GLA(0, 0, 1) GLA(0, 0, 2) GLA(0, 0, 3)
    GLB(0, 0, 0) GLB(0, 0, 1) GLB(0, 0, 2) GLB(0, 0, 3)
    __syncthreads();

    for (int kt = 0; kt < 16; kt++) {
        const int cur = kt & 1, nxt = cur ^ 1;
        const bool pf = (kt < 15);
        bf16x8 af[4][2], bfr[4][2];
        RDA(0, 0) RDA(0, 1) RDA(1, 0) RDA(1, 1)
        RDB(0, 0) RDB(0, 1) RDB(1, 0) RDB(1, 1)
        if (pf) { GLA(nxt, kt + 1, 0) GLA(nxt, kt + 1, 1) GLA(nxt, kt + 1, 2) }
        BARS MM(0, 0) BARE
        RDB(2, 0) RDB(2, 1) RDB(3, 0) RDB(3, 1)
        if (pf) { GLA(nxt, kt + 1, 3) GLB(nxt, kt + 1, 0) GLB(nxt, kt + 1, 1) }
        BARS MM(0, 2) BARE
        RDA(2, 0) RDA(2, 1) RDA(3, 0) RDA(3, 1)
        if (pf) { GLB(nxt, kt + 1, 2) GLB(nxt, kt + 1, 3) }
        BARS MM(2, 2) BARE
        __builtin_amdgcn_s_setprio(1);
        MM(2, 0)
        __builtin_amdgcn_s_setprio(0);
        asm volatile("s_waitcnt vmcnt(0)" ::: "memory");
        __builtin_amdgcn_s_barrier();
    }
#undef GLA
#undef GLB
#undef RDA
#undef RDB
#undef MM
#undef BARS
#undef BARE

    // ---- epilogues ----
    if (MODE == 1) {
        float* out = fout;
#pragma unroll
        for (int mt = 0; mt < 4; mt++)
#pragma unroll
            for (int nt = 0; nt < 4; nt++)
#pragma unroll
                for (int i = 0; i < 4; i++) {
                    size_t r = rowbase + wm + mt * 16 + lane_g * 4 + i;
                    int n = colbase + wn + nt * 16 + lane_r;
                    out[r * 1024 + n] = acc[mt][nt][i];
                }
    } else if (which <= 1) {
        unsigned short* out = which ? kbuf : qbuf;
#pragma unroll
        for (int a = 0; a < 4; a++) {
            int nbase = (colbase & 1023) + wn + a * 16 + 4 * lane_g;
            int h = nbase >> 6, d0 = nbase & 63;
#pragma unroll
            for (int b2 = 0; b2 < 4; b2++) {
                size_t r = rowbase + wm + b2 * 16 + lane_r;
                int bb  = (int)(r >> 11);
                int pos = (int)(r & 2047);
                float4 cs = *reinterpret_cast<const float4*>(
                    ropeb + pos * 64 + d0);          // {c0,s0,c1,s1}
                float a0 = acc[a][b2][0], a1 = acc[a][b2][1];
                float a2 = acc[a][b2][2], a3 = acc[a][b2][3];
                float o0 = (a0 * cs.x - a1 * cs.y) * scale;
                float o1 = (a0 * cs.y + a1 * cs.x) * scale;
                float o2 = (a2 * cs.z - a3 * cs.w) * scale;
                float o3 = (a2 * cs.w + a3 * cs.z) * scale;
                uint2 o;
                o.x = cvt_pk_bf16(o0, o1);
                o.y = cvt_pk_bf16(o2, o3);
                *reinterpret_cast<uint2*>(
                    out + (((size_t)(bb * NH_ + h)) * S_ + pos) * 64 + d0) = o;
            }
        }
    } else {
#pragma unroll
        for (int a = 0; a < 4; a++)
#pragma unroll
            for (int b2 = 0; b2 < 4; b2++) {
                size_t rr = rowbase + wm + a * 16 + lane_g * 4;
                int n = (colbase & 1023) + wn + b2 * 16 + lane_r;
                int bb  = (int)(rr >> 11);
                int pos = (int)(rr & 2047);
                int h = n >> 6, d = n & 63;
                ushort4 o;
                o.x = f2bf(acc[a][b2][0]); o.y = f2bf(acc[a][b2][1]);
                o.z = f2bf(acc[a][b2][2]); o.w = f2bf(acc[a][b2][3]);
                *reinterpret_cast<ushort4*>(
                    vtb + (((size_t)(bb * NH_ + h)) * 64 + d) * S_ + pos) = o;
            }
    }
}

// ---------------------------------------------------------------------------
// Flash attention, ROUND-14: 8-wave blocks (512 threads), 32 q per wave
// (1 q-block) -> 2 blocks/CU x 8 waves = 4 waves/SIMD (2x TLP vs round 13).
// K/V amortization unchanged (256 q/block). Masked bias is a post-QK add
// (cold path; identical math). sacc zero-init per tile (keeps VGPR <= 128,
// the observed cap for 512-thread kernels).
// ---------------------------------------------------------------------------
__global__ __launch_bounds__(512, 2) void attn_fwd(
    const unsigned short* __restrict__ qb, const unsigned short* __restrict__ kb,
    const unsigned short* __restrict__ vt, const float* __restrict__ biasb,
    const int* __restrict__ kflagb, unsigned short* __restrict__ ao)
{
    __shared__ alignas(16) unsigned short Kl[2][64 * 64];
    __shared__ alignas(16) unsigned short Vl[2][64 * 64];

    // XCD-clustering swizzle (bijective: 512 % 8 == 0): 8 bh per XCD.
    const int bid = blockIdx.x;
    const int xcd = bid & 7, idx = bid >> 3;
    const int bh = xcd * 8 + (idx >> 3);
    const int qt = idx & 7;                   // 8 q-tiles of 256 rows
    const int b = bh >> 4, h = bh & 15;

    const int t = threadIdx.x, l = t & 63, w = t >> 6;   // w = 0..7
    const int lr = l & 31;       // q column / frag row
    const int hi = l >> 5;
    const int row8 = lr & 7;     // read-swizzle key

    const unsigned short* qp = qb + (size_t)bh * S_ * 64;
    const unsigned short* kp = kb + (size_t)bh * S_ * 64;
    const unsigned short* vp = vt + (size_t)bh * 64 * S_;
    const float* bp = biasb + (size_t)b * S_;
    const int* kfl = kflagb + b * 32;

    // Q B-frags: qf[ks] = Q[qrow][d=16ks+8hi+j], qrow = qt*256 + w*32 + lr
    bf16x8 qf[4];
    {
        int qrow = qt * 256 + w * 32 + lr;
#pragma unroll
        for (int ks = 0; ks < 4; ks++)
            qf[ks] = *reinterpret_cast<const bf16x8*>(
                qp + (size_t)qrow * 64 + ks * 16 + hi * 8);
    }

    f32x16 oacc[2];
#pragma unroll
    for (int r = 0; r < 16; r++) { oacc[0][r] = 0.f; oacc[1][r] = 0.f; }
    float lsum = 0.f;

    // staging: wave w covers rows [w*8, w*8+8) of both tiles (1 chunk)
    const int grr = l >> 3;
    const int gss = ((l & 7) ^ grr) * 8;      // source-swizzled 16B slot

#define STAGE(bi, kt)                                                          \
    {                                                                          \
        int rbase = w * 8;                                                     \
        gload_lds16(kp + (size_t)((kt) * 64 + rbase + grr) * 64 + gss,         \
                    &Kl[bi][rbase * 64]);                                      \
        gload_lds16(vp + (size_t)(rbase + grr) * S_ + (kt) * 64 + gss,         \
                    &Vl[bi][rbase * 64]);                                      \
    }

    STAGE(0, 0)

    for (int kt = 0; kt < 32; kt++) {
        const int cur = kt & 1;
        __syncthreads();               // drains vmcnt: buf[cur] ready; prev reads done
        if (kt < 31) STAGE(cur ^ 1, kt + 1)

        // S^T = K x Q, zero C-init
        f32x16 sacc[2];
        {
            f32x16 zz;
#pragma unroll
            for (int r = 0; r < 16; r++) zz[r] = 0.f;
            __builtin_amdgcn_s_setprio(1);
#pragma unroll
            for (int T = 0; T < 2; T++) {
                int rowb = (32 * T + lr) * 128;
                bf16x8 kf0 = *reinterpret_cast<const bf16x8*>(
                    (const char*)Kl[cur] + rowb + ((hi ^ row8) << 4));
                sacc[T] = mfma32(kf0, qf[0], zz);
#pragma unroll
                for (int ks = 1; ks < 4; ks++) {
                    bf16x8 kfk = *reinterpret_cast<const bf16x8*>(
                        (const char*)Kl[cur] + rowb + (((2 * ks + hi) ^ row8) << 4));
                    sacc[T] = mfma32(kfk, qf[ks], sacc[T]);
                }
            }
            __builtin_amdgcn_s_setprio(0);
        }
        // masked tiles (cold path): additive bias after QK^T -- same math
        if (!kfl[kt]) {
#pragma unroll
            for (int T = 0; T < 2; T++)
#pragma unroll
                for (int g = 0; g < 4; g++) {
                    float4 bv = *reinterpret_cast<const float4*>(
                        bp + kt * 64 + T * 32 + g * 8 + hi * 4);
                    sacc[T][g * 4 + 0] += bv.x; sacc[T][g * 4 + 1] += bv.y;
                    sacc[T][g * 4 + 2] += bv.z; sacc[T][g * 4 + 3] += bv.w;
                }
        }

        // p = exp2(s), sum, pack, permlane-redistribute
        unsigned u[2][8];
        float r0 = 0.f, r1 = 0.f, r2 = 0.f, r3 = 0.f;
#pragma unroll
        for (int T = 0; T < 2; T++) {
            float p[16];
#pragma unroll
            for (int r = 0; r < 16; r++) p[r] = EXP2F(sacc[T][r]);
#pragma unroll
            for (int r = 0; r < 16; r += 4) {
                r0 += p[r]; r1 += p[r + 1]; r2 += p[r + 2]; r3 += p[r + 3];
            }
#pragma unroll
            for (int bq = 0; bq < 4; bq++) {
                u[T][bq * 2 + 0] = cvt_pk_bf16(p[bq * 4 + 0], p[bq * 4 + 1]);
                u[T][bq * 2 + 1] = cvt_pk_bf16(p[bq * 4 + 2], p[bq * 4 + 3]);
            }
        }
        lsum += (r0 + r1) + (r2 + r3);

        bf16x8 pa[4];
#pragma unroll
        for (int ks = 0; ks < 4; ks++) {
            int T = ks >> 1, e = ks & 1;
            unsigned a0 = u[T][4 * e + 0], b0 = u[T][4 * e + 2];
            unsigned a1 = u[T][4 * e + 1], b1 = u[T][4 * e + 3];
            perm32swap(a0, b0);
            perm32swap(a1, b1);
            unsigned q4[4] = {a0, a1, b0, b1};
            pa[ks] = *reinterpret_cast<const bf16x8*>(q4);
        }

        // O^T += V^T x P^T
        __builtin_amdgcn_s_setprio(1);
#pragma unroll
        for (int dt = 0; dt < 2; dt++) {
            int rowb = (32 * dt + lr) * 128;
#pragma unroll
            for (int ks = 0; ks < 4; ks++) {
                bf16x8 vf = *reinterpret_cast<const bf16x8*>(
                    (const char*)Vl[cur] + rowb + (((2 * ks + hi) ^ row8) << 4));
                oacc[dt] = mfma32(vf, pa[ks], oacc[dt]);
            }
        }
        __builtin_amdgcn_s_setprio(0);
    }
#undef STAGE

    // epilogue: O row d = 32dt+8g+4hi+m, col q = lr
    lsum += __shfl_xor(lsum, 32);
    float rl = 1.0f / lsum;
    size_t obase = ((size_t)(b * S_) + qt * 256 + w * 32 + lr) * 1024 + h * 64;
#pragma unroll
    for (int dt = 0; dt < 2; dt++)
#pragma unroll
        for (int g = 0; g < 4; g++) {
            uint2 o;
            o.x = cvt_pk_bf16(oacc[dt][g * 4 + 0] * rl, oacc[dt][g * 4 + 1] * rl);
            o.y = cvt_pk_bf16(oacc[dt][g * 4 + 2] * rl, oacc[dt][g * 4 + 3] * rl);
            *reinterpret_cast<uint2*>(ao + obase + 32 * dt + 8 * g + 4 * hi) = o;
        }
}

// ---------------------------------------------------------------------------
extern "C" void kernel_launch(void* const* d_in, const int* in_sizes, int n_in,
                              void* d_out, int out_size, void* d_ws, size_t ws_size,
                              hipStream_t stream)
{
    const float* x  = (const float*)d_in[0];
    const float* wq = (const float*)d_in[1];
    const float* wk = (const float*)d_in[2];
    const float* wv = (const float*)d_in[3];
    const float* wo = (const float*)d_in[4];
    const int* mask = (const int*)d_in[5];

    unsigned short* ws   = (unsigned short*)d_ws;
    unsigned short* xb   = ws;                 // M*K bf16; reused as attn-out
    unsigned short* wqkv = ws + 8388608;       // [3072 x 1024] stacked Q,K,V
    unsigned short* wob  = ws + 11534336;
    unsigned short* qbuf = ws + 12582912;
    unsigned short* kbuf = ws + 20971520;
    unsigned short* vtb  = ws + 29360128;
    float* ropeb = (float*)(ws + 37748736);    // [S][32][2] {cos,sin}
    float* biasb = (float*)(ws + 38010880);
    int* kflagb  = (int*)(biasb + 8192);
    unsigned short* aob = xb;                  // alias: xb dead after QKV GEMM

    // conversion + rope/bias/flag tables in one launch
    prep_convert<<<12544, 256, 0, stream>>>(
        x, wq, wk, wv, wo, ws, mask, (float2*)ropeb, biasb, kflagb);

    // Fused QKV projection, 128^2 4-phase (Q scale = 0.125*log2e in epilogue)
    gemm_main<0><<<dim3(24, 64), 256, 0, stream>>>(
        xb, wqkv, qbuf, kbuf, vtb, nullptr, ropeb);

    attn_fwd<<<512, 512, 0, stream>>>(qbuf, kbuf, vtb, biasb, kflagb, aob);

    gemm_main<1><<<dim3(8, 64), 256, 0, stream>>>(
        aob, wob, nullptr, nullptr, nullptr, (float*)d_out, nullptr);
}